// Round 5
// baseline (403.566 us; speedup 1.0000x reference)
//
#include <hip/hip_runtime.h>
#include <stdint.h>

typedef __attribute__((ext_vector_type(4)))  int i32x4;
typedef __attribute__((ext_vector_type(16))) int i32x16;

#define M_TOK 8192
#define N_OUT 4096
#define K_IN  4096

// gemm geometry: 256x256 tile, BK = 64 i8, FOUR waves in a 2x2 grid,
// per-wave 128x128 output = 4x4 of mfma_i32_32x32x32_i8.
// Rationale: per K-tile per CU the LDS-read pipe was the critical pipe
// (96 reads ~1790cyc vs 1170 MFMA) due to 4x A / 2x B read redundancy at
// 8 waves. 4 waves x (4m x 4n) cuts frag reads to 64 (~770cyc) -> MFMA
// becomes the only critical pipe. Costs ~415 VGPR -> 1 wave/SIMD; ILP via
// cross-barrier register prefetch replaces TLP.
#define BM 256
#define BN 256
#define BKB 64            // bytes of K per tile
#define NT (K_IN / BKB)   // 64 K-tiles
#define SLOT_BYTES 32768  // A 16KB + B 16KB per slot
#define B_OFF 16384

// global->LDS direct copy, 16B per lane. LDS dest MUST be the wave-uniform
// base: HW writes lane L's 16B at (base + L*16).
#define GLDS16(gp, lp)                                                         \
  __builtin_amdgcn_global_load_lds(                                            \
      (const __attribute__((address_space(1))) void*)(gp),                     \
      (__attribute__((address_space(3))) void*)(lp), 16, 0, 0)

#define VM16 asm volatile("s_waitcnt vmcnt(16)" ::: "memory")
#define VM8  asm volatile("s_waitcnt vmcnt(8)" ::: "memory")
#define VM0  asm volatile("s_waitcnt vmcnt(0)" ::: "memory")
#define SB0  __builtin_amdgcn_sched_barrier(0)
#define NOPX ((void)0)

// ---------------------------------------------------------------------------
// Fused quantization: blocks [0, M_TOK) do per-row i8 quant of x;
// blocks [M_TOK, M_TOK+4096) do sign(w) -> i8.
// ---------------------------------------------------------------------------
__global__ void __launch_bounds__(256) quant_fused(
    const float* __restrict__ x, const float* __restrict__ w,
    char* __restrict__ xq, char* __restrict__ wq, float* __restrict__ scales) {
  __shared__ float wmax[4];
  const int t = threadIdx.x;

  if (blockIdx.x < M_TOK) {
    const int row = blockIdx.x;
    const float4* rp = (const float4*)(x + (size_t)row * K_IN);

    float4 v[4];
#pragma unroll
    for (int p = 0; p < 4; p++) v[p] = rp[p * 256 + t];

    float amax = 0.f;
#pragma unroll
    for (int p = 0; p < 4; p++)
      amax = fmaxf(amax, fmaxf(fmaxf(fabsf(v[p].x), fabsf(v[p].y)),
                               fmaxf(fabsf(v[p].z), fabsf(v[p].w))));

#pragma unroll
    for (int off = 32; off > 0; off >>= 1)
      amax = fmaxf(amax, __shfl_xor(amax, off));

    if ((t & 63) == 0) wmax[t >> 6] = amax;
    __syncthreads();
    amax = fmaxf(fmaxf(wmax[0], wmax[1]), fmaxf(wmax[2], wmax[3]));
    amax = fmaxf(amax, 1e-30f);

    const float inv = 127.f / amax;
    if (t == 0) scales[row] = amax / 127.f;

    uint32_t* op = (uint32_t*)(xq + (size_t)row * K_IN);
#pragma unroll
    for (int p = 0; p < 4; p++) {
      uint32_t b0 = (uint32_t)(__float2int_rn(v[p].x * inv) & 0xFF);
      uint32_t b1 = (uint32_t)(__float2int_rn(v[p].y * inv) & 0xFF);
      uint32_t b2 = (uint32_t)(__float2int_rn(v[p].z * inv) & 0xFF);
      uint32_t b3 = (uint32_t)(__float2int_rn(v[p].w * inv) & 0xFF);
      op[p * 256 + t] = b0 | (b1 << 8) | (b2 << 16) | (b3 << 24);
    }
  } else {
    const size_t base = (size_t)(blockIdx.x - M_TOK) * 1024;  // float4 units
    const float4* p = (const float4*)w + base;
    uint32_t* op = (uint32_t*)wq + base;
#pragma unroll
    for (int q = 0; q < 4; q++) {
      float4 f = p[q * 256 + t];
      int s0 = (f.x > 0.f) - (f.x < 0.f);
      int s1 = (f.y > 0.f) - (f.y < 0.f);
      int s2 = (f.z > 0.f) - (f.z < 0.f);
      int s3 = (f.w > 0.f) - (f.w < 0.f);
      op[q * 256 + t] = (uint32_t)(s0 & 0xFF) | ((uint32_t)(s1 & 0xFF) << 8) |
                        ((uint32_t)(s2 & 0xFF) << 16) | ((uint32_t)(s3 & 0xFF) << 24);
    }
  }
}

// ---------------------------------------------------------------------------
// C[m][n] = scale[m] * (sum_k Aq[m][k] * Wq[n][k]) + bias[n]
//
// 4-slot ring, prefetch distance 3, counted vmcnt, 1 barrier/tile,
// cross-barrier register prefetch (iteration t's MFMAs consume fragments read
// during iteration t-1).
//
// vmcnt accounting (8 GLDS/tile/wave): at ITER(t) outstanding = tiles
// {t+1, t+2} = 16 loads; READF(t+1) needs t+1 -> vmcnt(8). Prologue stages
// {0,1,2} = 24; READF(0) -> vmcnt(16). Tail drains 8 -> 0.
//
// WAR: stage(t+3) at ITER(t) overwrites slot of tile t-1; t-1's frag reads
// were lgkm-complete before ITER(t-1)'s MFMAs (compiler waitcnt), hence
// before ITER(t)'s barrier -> safe for all waves.
//
// LDS swizzle (unchanged): row r stores 16B chunk c at slot c ^ ((r>>1)&3);
// global source pre-swizzled (lane L: chunk (L&3)^((L>>3)&3)); fragment reads
// spread every 8 rows over all 32 banks.
// ---------------------------------------------------------------------------
struct Frags {
  i32x4 a[2][4];  // [ks][m]
  i32x4 b[2][4];  // [ks][n]
};

__global__ void __launch_bounds__(256, 1) gemm_bin_i8(
    const char* __restrict__ A, const char* __restrict__ B,
    const float* __restrict__ scales, const float* __restrict__ bias,
    float* __restrict__ C) {
  __shared__ __align__(16) char lds[4 * SLOT_BYTES];  // 128 KB

  const int tid  = threadIdx.x;
  const int lane = tid & 63;
  const int wv   = tid >> 6;   // 0..3
  const int wm   = wv >> 1;    // 0..1  (M half)
  const int wn   = wv & 1;     // 0..1  (N half)

  // XCD-aware bijective swizzle: 512 blocks, 8 XCDs, 64 per XCD chunk.
  int bid = (int)blockIdx.x;
  bid = (bid & 7) * (512 >> 3) + (bid >> 3);
  const int m0 = (bid >> 4) * BM;  // 32 m-tiles
  const int n0 = (bid & 15) * BN;  // 16 n-tiles

  // ---- staging: wave wv owns rows [wv*64, wv*64+64) of A and of B;
  // 4 GLDS16 each (16 rows / 1024 B per instruction).
  const int srow   = lane >> 2;                       // 0..15
  const int schunk = (lane & 3) ^ ((lane >> 3) & 3);  // pre-swizzled source chunk
  const char* gAb = A + (size_t)(m0 + wv * 64 + srow) * K_IN + schunk * 16;
  const char* gBb = B + (size_t)(n0 + wv * 64 + srow) * K_IN + schunk * 16;
  // WAVE-UNIFORM LDS bases (HW adds lane*16 itself).
  char* lAb = lds + wv * 4096;
  char* lBb = lds + B_OFF + wv * 4096;

  auto stage = [&](int tt) {
    const size_t ko = (size_t)tt * BKB;
    char* la = lAb + (tt & 3) * SLOT_BYTES;
    char* lb = lBb + (tt & 3) * SLOT_BYTES;
#pragma unroll
    for (int g = 0; g < 4; g++)
      GLDS16(gAb + ko + (size_t)(g * 16) * K_IN, la + g * 1024);
#pragma unroll
    for (int g = 0; g < 4; g++)
      GLDS16(gBb + ko + (size_t)(g * 16) * K_IN, lb + g * 1024);
  };

  // ---- fragment read constants
  const int fr  = lane & 31;         // row within 32-row subtile
  const int k16 = lane >> 5;         // which 16B half of the 32-i8 k-slice
  const int x3  = (lane >> 1) & 3;   // swizzle term ((row>>1)&3)
  const int aoff = wm * 8192 + fr * 64;           // wm*128 rows
  const int boff = B_OFF + wn * 8192 + fr * 64;   // wn*128 rows
  const int so0 = ((0 + k16) ^ x3) << 4;          // ks=0 chunk offset
  const int so1 = ((2 + k16) ^ x3) << 4;          // ks=1 chunk offset

  i32x16 acc[4][4];
#pragma unroll
  for (int m = 0; m < 4; m++)
#pragma unroll
    for (int n = 0; n < 4; n++)
#pragma unroll
      for (int r = 0; r < 16; r++) acc[m][n][r] = 0;

  Frags f0, f1;

#define READF(f, tt)                                                           \
  {                                                                            \
    const char* pA_ = lds + ((tt) & 3) * SLOT_BYTES + aoff;                    \
    const char* pB_ = lds + ((tt) & 3) * SLOT_BYTES + boff;                    \
    f.a[0][0] = *(const i32x4*)(pA_ + so0);                                    \
    f.a[0][1] = *(const i32x4*)(pA_ + 2048 + so0);                             \
    f.a[0][2] = *(const i32x4*)(pA_ + 4096 + so0);                             \
    f.a[0][3] = *(const i32x4*)(pA_ + 6144 + so0);                             \
    f.b[0][0] = *(const i32x4*)(pB_ + so0);                                    \
    f.b[0][1] = *(const i32x4*)(pB_ + 2048 + so0);                             \
    f.b[0][2] = *(const i32x4*)(pB_ + 4096 + so0);                             \
    f.b[0][3] = *(const i32x4*)(pB_ + 6144 + so0);                             \
    f.a[1][0] = *(const i32x4*)(pA_ + so1);                                    \
    f.a[1][1] = *(const i32x4*)(pA_ + 2048 + so1);                             \
    f.a[1][2] = *(const i32x4*)(pA_ + 4096 + so1);                             \
    f.a[1][3] = *(const i32x4*)(pA_ + 6144 + so1);                             \
    f.b[1][0] = *(const i32x4*)(pB_ + so1);                                    \
    f.b[1][1] = *(const i32x4*)(pB_ + 2048 + so1);                             \
    f.b[1][2] = *(const i32x4*)(pB_ + 4096 + so1);                             \
    f.b[1][3] = *(const i32x4*)(pB_ + 6144 + so1);                             \
  }

#define MFMA1(ks, f)                                                           \
  {                                                                            \
    acc[0][0] = __builtin_amdgcn_mfma_i32_32x32x32_i8(f.a[ks][0], f.b[ks][0], acc[0][0], 0, 0, 0); \
    acc[0][1] = __builtin_amdgcn_mfma_i32_32x32x32_i8(f.a[ks][0], f.b[ks][1], acc[0][1], 0, 0, 0); \
    acc[0][2] = __builtin_amdgcn_mfma_i32_32x32x32_i8(f.a[ks][0], f.b[ks][2], acc[0][2], 0, 0, 0); \
    acc[0][3] = __builtin_amdgcn_mfma_i32_32x32x32_i8(f.a[ks][0], f.b[ks][3], acc[0][3], 0, 0, 0); \
    acc[1][0] = __builtin_amdgcn_mfma_i32_32x32x32_i8(f.a[ks][1], f.b[ks][0], acc[1][0], 0, 0, 0); \
    acc[1][1] = __builtin_amdgcn_mfma_i32_32x32x32_i8(f.a[ks][1], f.b[ks][1], acc[1][1], 0, 0, 0); \
    acc[1][2] = __builtin_amdgcn_mfma_i32_32x32x32_i8(f.a[ks][1], f.b[ks][2], acc[1][2], 0, 0, 0); \
    acc[1][3] = __builtin_amdgcn_mfma_i32_32x32x32_i8(f.a[ks][1], f.b[ks][3], acc[1][3], 0, 0, 0); \
    acc[2][0] = __builtin_amdgcn_mfma_i32_32x32x32_i8(f.a[ks][2], f.b[ks][0], acc[2][0], 0, 0, 0); \
    acc[2][1] = __builtin_amdgcn_mfma_i32_32x32x32_i8(f.a[ks][2], f.b[ks][1], acc[2][1], 0, 0, 0); \
    acc[2][2] = __builtin_amdgcn_mfma_i32_32x32x32_i8(f.a[ks][2], f.b[ks][2], acc[2][2], 0, 0, 0); \
    acc[2][3] = __builtin_amdgcn_mfma_i32_32x32x32_i8(f.a[ks][2], f.b[ks][3], acc[2][3], 0, 0, 0); \
    acc[3][0] = __builtin_amdgcn_mfma_i32_32x32x32_i8(f.a[ks][3], f.b[ks][0], acc[3][0], 0, 0, 0); \
    acc[3][1] = __builtin_amdgcn_mfma_i32_32x32x32_i8(f.a[ks][3], f.b[ks][1], acc[3][1], 0, 0, 0); \
    acc[3][2] = __builtin_amdgcn_mfma_i32_32x32x32_i8(f.a[ks][3], f.b[ks][2], acc[3][2], 0, 0, 0); \
    acc[3][3] = __builtin_amdgcn_mfma_i32_32x32x32_i8(f.a[ks][3], f.b[ks][3], acc[3][3], 0, 0, 0); \
  }

#define MFMAF(f)                                                               \
  {                                                                            \
    __builtin_amdgcn_s_setprio(1);                                             \
    MFMA1(0, f);                                                               \
    MFMA1(1, f);                                                               \
    __builtin_amdgcn_s_setprio(0);                                             \
  }

  // iter t: wait t+1 landed -> barrier -> stage t+3 + read t+1 frags (LDS
  // pipe) while MFMAs on tile t run from registers (matrix pipe).
#define ITER(t_, fc, fn, STAGE_STMT, VM_STMT)                                  \
  {                                                                            \
    VM_STMT;                                                                   \
    SB0;                                                                       \
    __builtin_amdgcn_s_barrier();                                              \
    SB0;                                                                       \
    STAGE_STMT;                                                                \
    READF(fn, (t_) + 1);                                                       \
    MFMAF(fc);                                                                 \
  }

  // ---- prologue: stage tiles 0,1,2 (24 loads); tile 0 readable.
  stage(0); stage(1); stage(2);
  VM16;  // tile 0 done (tiles 1,2 in flight)
  SB0;
  __builtin_amdgcn_s_barrier();
  SB0;
  READF(f0, 0);

  // ---- main loop: trips I=0..29 cover t=0..59 (stages 3..62)
  for (int I = 0; I < 30; ++I) {
    const int t0 = 2 * I;
    ITER(t0,     f0, f1, stage(t0 + 3), VM8);
    ITER(t0 + 1, f1, f0, stage(t0 + 4), VM8);
  }
  // ---- tail: t=60 (stage 63), 61, 62, then t=63 from registers
  ITER(60, f0, f1, stage(63), VM8);
  ITER(61, f1, f0, NOPX, VM8);
  ITER(62, f0, f1, NOPX, VM0);
  MFMAF(f1);  // t=63 (lgkm use-wait covers f1)
#undef ITER
#undef MFMAF
#undef MFMA1
#undef READF

  // ---- epilogue: 32x32 C/D layout col=lane&31, row=(r&3)+8*(r>>2)+4*(lane>>5)
  const int col0 = n0 + wn * 128 + (lane & 31);
  float bv[4];
#pragma unroll
  for (int n = 0; n < 4; n++) bv[n] = bias[col0 + n * 32];
#pragma unroll
  for (int m = 0; m < 4; m++) {
    const int rb = m0 + wm * 128 + m * 32 + ((lane >> 5) << 2);
#pragma unroll
    for (int r = 0; r < 16; r++) {
      const int row = rb + (r & 3) + ((r >> 2) << 3);
      const float sc = scales[row];
      float* cp = C + (size_t)row * N_OUT + col0;
      cp[0]  = (float)acc[m][0][r] * sc + bv[0];
      cp[32] = (float)acc[m][1][r] * sc + bv[1];
      cp[64] = (float)acc[m][2][r] * sc + bv[2];
      cp[96] = (float)acc[m][3][r] * sc + bv[3];
    }
  }
}

// emergency fallback if ws too small (correct but slow)
__global__ void fallback_gemm(const float* __restrict__ x, const float* __restrict__ w,
                              const float* __restrict__ bias, float* __restrict__ out) {
  int idx = blockIdx.x * blockDim.x + threadIdx.x;
  if (idx >= M_TOK * N_OUT) return;
  int row = idx / N_OUT, col = idx % N_OUT;
  const float* xp = x + (size_t)row * K_IN;
  const float* wp = w + (size_t)col * K_IN;
  float s = 0.f;
  for (int k = 0; k < K_IN; k++) {
    float wv = wp[k];
    float sg = wv > 0.f ? 1.f : (wv < 0.f ? -1.f : 0.f);
    s += xp[k] * sg;
  }
  out[idx] = s + bias[col];
}

extern "C" void kernel_launch(void* const* d_in, const int* in_sizes, int n_in,
                              void* d_out, int out_size, void* d_ws, size_t ws_size,
                              hipStream_t stream) {
  const float* x    = (const float*)d_in[0];
  const float* w    = (const float*)d_in[1];
  const float* bias = (const float*)d_in[2];
  float* out = (float*)d_out;

  const size_t xq_bytes = (size_t)M_TOK * K_IN;           // 32 MiB
  const size_t wq_bytes = (size_t)N_OUT * K_IN;           // 16 MiB
  const size_t sc_bytes = (size_t)M_TOK * sizeof(float);  // 32 KiB

  if (ws_size < xq_bytes + wq_bytes + sc_bytes) {
    int total = M_TOK * N_OUT;
    fallback_gemm<<<(total + 255) / 256, 256, 0, stream>>>(x, w, bias, out);
    return;
  }

  char*  xq = (char*)d_ws;
  char*  wq = (char*)d_ws + xq_bytes;
  float* sc = (float*)((char*)d_ws + xq_bytes + wq_bytes);

  // one fused quant launch: 8192 x-row blocks + 4096 w-sign blocks
  quant_fused<<<M_TOK + (N_OUT * K_IN / 4) / 1024, 256, 0, stream>>>(x, w, xq, wq, sc);

  // 32 x 16 = 512 blocks of 256 threads (4 waves), 128 KB LDS -> 1 block/CU
  gemm_bin_i8<<<512, 256, 0, stream>>>(xq, wq, sc, bias, out);
}

// Round 6
// 388.087 us; speedup vs baseline: 1.0399x; 1.0399x over previous
//
#include <hip/hip_runtime.h>
#include <stdint.h>

typedef __attribute__((ext_vector_type(4)))  int i32x4;
typedef __attribute__((ext_vector_type(16))) int i32x16;

#define M_TOK 8192
#define N_OUT 4096
#define K_IN  4096

// gemm geometry: 256x256 tile, BK = 64 i8 (64 B/row), 8 waves (2Mx4N),
// per-wave 128x64 output = 4x2 of mfma_i32_32x32x32_i8.
#define BM 256
#define BN 256
#define BKB 64            // bytes of K per tile
#define NT (K_IN / BKB)   // 64 K-tiles
#define SLOT_BYTES 32768  // A 16KB + B 16KB per slot
#define B_OFF 16384

// global->LDS direct copy, 16B per lane. LDS dest MUST be the wave-uniform
// base: HW writes lane L's 16B at (base + L*16).
#define GLDS16(gp, lp)                                                         \
  __builtin_amdgcn_global_load_lds(                                            \
      (const __attribute__((address_space(1))) void*)(gp),                     \
      (__attribute__((address_space(3))) void*)(lp), 16, 0, 0)

#define VM4 asm volatile("s_waitcnt vmcnt(4)" ::: "memory")
#define VM8 asm volatile("s_waitcnt vmcnt(8)" ::: "memory")
#define VM0 asm volatile("s_waitcnt vmcnt(0)" ::: "memory")
#define SB0 __builtin_amdgcn_sched_barrier(0)
// sched_group_barrier masks: MFMA=0x8, DS_READ=0x100
#define SGB_DS2 __builtin_amdgcn_sched_group_barrier(0x100, 2, 0)
#define SGB_MF2 __builtin_amdgcn_sched_group_barrier(0x008, 2, 0)
#define SGB_MF4 __builtin_amdgcn_sched_group_barrier(0x008, 4, 0)
#define NOPX ((void)0)

// ---------------------------------------------------------------------------
// Fused quantization: blocks [0, M_TOK) do per-row i8 quant of x;
// blocks [M_TOK, M_TOK+4096) do sign(w) -> i8.
// ---------------------------------------------------------------------------
__global__ void __launch_bounds__(256) quant_fused(
    const float* __restrict__ x, const float* __restrict__ w,
    char* __restrict__ xq, char* __restrict__ wq, float* __restrict__ scales) {
  __shared__ float wmax[4];
  const int t = threadIdx.x;

  if (blockIdx.x < M_TOK) {
    const int row = blockIdx.x;
    const float4* rp = (const float4*)(x + (size_t)row * K_IN);

    float4 v[4];
#pragma unroll
    for (int p = 0; p < 4; p++) v[p] = rp[p * 256 + t];

    float amax = 0.f;
#pragma unroll
    for (int p = 0; p < 4; p++)
      amax = fmaxf(amax, fmaxf(fmaxf(fabsf(v[p].x), fabsf(v[p].y)),
                               fmaxf(fabsf(v[p].z), fabsf(v[p].w))));

#pragma unroll
    for (int off = 32; off > 0; off >>= 1)
      amax = fmaxf(amax, __shfl_xor(amax, off));

    if ((t & 63) == 0) wmax[t >> 6] = amax;
    __syncthreads();
    amax = fmaxf(fmaxf(wmax[0], wmax[1]), fmaxf(wmax[2], wmax[3]));
    amax = fmaxf(amax, 1e-30f);

    const float inv = 127.f / amax;
    if (t == 0) scales[row] = amax / 127.f;

    uint32_t* op = (uint32_t*)(xq + (size_t)row * K_IN);
#pragma unroll
    for (int p = 0; p < 4; p++) {
      uint32_t b0 = (uint32_t)(__float2int_rn(v[p].x * inv) & 0xFF);
      uint32_t b1 = (uint32_t)(__float2int_rn(v[p].y * inv) & 0xFF);
      uint32_t b2 = (uint32_t)(__float2int_rn(v[p].z * inv) & 0xFF);
      uint32_t b3 = (uint32_t)(__float2int_rn(v[p].w * inv) & 0xFF);
      op[p * 256 + t] = b0 | (b1 << 8) | (b2 << 16) | (b3 << 24);
    }
  } else {
    const size_t base = (size_t)(blockIdx.x - M_TOK) * 1024;  // float4 units
    const float4* p = (const float4*)w + base;
    uint32_t* op = (uint32_t*)wq + base;
#pragma unroll
    for (int q = 0; q < 4; q++) {
      float4 f = p[q * 256 + t];
      int s0 = (f.x > 0.f) - (f.x < 0.f);
      int s1 = (f.y > 0.f) - (f.y < 0.f);
      int s2 = (f.z > 0.f) - (f.z < 0.f);
      int s3 = (f.w > 0.f) - (f.w < 0.f);
      op[q * 256 + t] = (uint32_t)(s0 & 0xFF) | ((uint32_t)(s1 & 0xFF) << 8) |
                        ((uint32_t)(s2 & 0xFF) << 16) | ((uint32_t)(s3 & 0xFF) << 24);
    }
  }
}

// ---------------------------------------------------------------------------
// C[m][n] = scale[m] * (sum_k Aq[m][k] * Wq[n][k]) + bias[n]
//
// R4 ring (4 slots, prefetch dist 3, counted vmcnt, 1 barrier/tile, register
// double-buffer) + FINE INTERLEAVE of {reads for tile t+1} with {MFMAs on
// tile t}, pinned via sched_group_barrier: 6 x {2 ds_read, 2 MFMA} + 4-MFMA
// tail. Rationale: waves issue in-order; with reads clustered before MFMAs,
// the CU-shared LDS pipe (96 reads ~1150 cyc/tile) gates when ANY wave
// reaches its MFMAs -> measured tile time ~ LDS + MFMA serial sum (2709 cyc,
// MfmaUtil 42%). Interleaving lets the two pipes run concurrently.
//
// vmcnt accounting (4 GLDS/tile/wave): at ITER(t) entry outstanding = tiles
// {t+1, t+2} = 8; VM4 -> tile t+1 landed (vmcnt retires in issue order).
// Barrier extends to all waves -> reads of t+1 safe. stage(t+3) overwrites
// slot (t-1)&3: t-1's reads completed before ITER(t-1)'s MFMA issue
// (compiler lgkmcnt) < this barrier -> WAR safe for all waves.
//
// LDS swizzle: row r stores 16B chunk c at slot c ^ ((r>>1)&3); global source
// pre-swizzled (lane L: chunk (L&3)^((L>>3)&3)); fragment reads spread every
// 8 rows over all 32 banks (conflict-free in 8-lane groups).
// ---------------------------------------------------------------------------
struct Frags {
  i32x4 a[2][4];  // [ks][m]
  i32x4 b[2][2];  // [ks][n]
};

__global__ void __launch_bounds__(512, 2) gemm_bin_i8(
    const char* __restrict__ A, const char* __restrict__ B,
    const float* __restrict__ scales, const float* __restrict__ bias,
    float* __restrict__ C) {
  __shared__ __align__(16) char lds[4 * SLOT_BYTES];  // 128 KB

  const int tid  = threadIdx.x;
  const int lane = tid & 63;
  const int wv   = tid >> 6;   // 0..7
  const int wm   = wv >> 2;    // 0..1  (M half)
  const int wn   = wv & 3;     // 0..3  (N quarter)

  // XCD-aware bijective swizzle: 512 blocks, 8 XCDs, 64 per XCD chunk.
  int bid = (int)blockIdx.x;
  bid = (bid & 7) * (512 >> 3) + (bid >> 3);
  const int m0 = (bid >> 4) * BM;  // 32 m-tiles
  const int n0 = (bid & 15) * BN;  // 16 n-tiles

  // ---- staging: wave wv owns rows [wv*32, wv*32+32); 2 GLDS16 each for A,B.
  const int srow   = lane >> 2;                       // 0..15
  const int schunk = (lane & 3) ^ ((lane >> 3) & 3);  // pre-swizzled source chunk
  const char* gAb = A + (size_t)(m0 + wv * 32 + srow) * K_IN + schunk * 16;
  const char* gBb = B + (size_t)(n0 + wv * 32 + srow) * K_IN + schunk * 16;
  // WAVE-UNIFORM LDS bases (HW adds lane*16 itself).
  char* lAb = lds + wv * 2048;
  char* lBb = lds + B_OFF + wv * 2048;

  auto stage = [&](int tt) {
    const size_t ko = (size_t)tt * BKB;
    char* la = lAb + (tt & 3) * SLOT_BYTES;
    char* lb = lBb + (tt & 3) * SLOT_BYTES;
    GLDS16(gAb + ko, la);
    GLDS16(gAb + ko + (size_t)16 * K_IN, la + 1024);
    GLDS16(gBb + ko, lb);
    GLDS16(gBb + ko + (size_t)16 * K_IN, lb + 1024);
  };

  // ---- fragment read constants
  const int fr  = lane & 31;         // row within 32-row subtile
  const int k16 = lane >> 5;         // which 16B half of the 32-i8 k-slice
  const int x3  = (lane >> 1) & 3;   // swizzle term ((row>>1)&3)
  const int aoff = wm * 8192 + fr * 64;           // wm*128 rows
  const int boff = B_OFF + wn * 4096 + fr * 64;   // wn*64 rows
  const int so0 = ((0 + k16) ^ x3) << 4;          // ks=0 chunk offset
  const int so1 = ((2 + k16) ^ x3) << 4;          // ks=1 chunk offset

  i32x16 acc[4][2];
#pragma unroll
  for (int m = 0; m < 4; m++)
#pragma unroll
    for (int n = 0; n < 2; n++)
#pragma unroll
      for (int r = 0; r < 16; r++) acc[m][n][r] = 0;

  Frags f0, f1;

#define MFMA_(ks, mi, ni, f)                                                   \
  acc[mi][ni] = __builtin_amdgcn_mfma_i32_32x32x32_i8(f.a[ks][mi], f.b[ks][ni],\
                                                      acc[mi][ni], 0, 0, 0)

  // plain (non-interleaved) fragment read — prologue only
#define READF(f, tt)                                                           \
  {                                                                            \
    const char* pA_ = lds + ((tt) & 3) * SLOT_BYTES + aoff;                    \
    const char* pB_ = lds + ((tt) & 3) * SLOT_BYTES + boff;                    \
    f.a[0][0] = *(const i32x4*)(pA_ + so0);                                    \
    f.a[0][1] = *(const i32x4*)(pA_ + 2048 + so0);                             \
    f.a[0][2] = *(const i32x4*)(pA_ + 4096 + so0);                             \
    f.a[0][3] = *(const i32x4*)(pA_ + 6144 + so0);                             \
    f.b[0][0] = *(const i32x4*)(pB_ + so0);                                    \
    f.b[0][1] = *(const i32x4*)(pB_ + 2048 + so0);                             \
    f.a[1][0] = *(const i32x4*)(pA_ + so1);                                    \
    f.a[1][1] = *(const i32x4*)(pA_ + 2048 + so1);                             \
    f.a[1][2] = *(const i32x4*)(pA_ + 4096 + so1);                             \
    f.a[1][3] = *(const i32x4*)(pA_ + 6144 + so1);                             \
    f.b[1][0] = *(const i32x4*)(pB_ + so1);                                    \
    f.b[1][1] = *(const i32x4*)(pB_ + 2048 + so1);                             \
    f.b[1][2] = *(const i32x4*)(pB_ + so1);  /* dummy overwritten below */     \
  }

  // Fine interleave: 6 x {2 ds_read (f_next), 2 MFMA (f_cur)} + 4-MFMA tail.
  // sched_group_barrier pins emission order; reads and MFMAs touch disjoint
  // registers so no lgkm wait is inserted inside the cluster.
#define CLUSTER(fc, fn, tt)                                                    \
  {                                                                            \
    const char* pA_ = lds + ((tt) & 3) * SLOT_BYTES + aoff;                    \
    const char* pB_ = lds + ((tt) & 3) * SLOT_BYTES + boff;                    \
    __builtin_amdgcn_s_setprio(1);                                             \
    fn.a[0][0] = *(const i32x4*)(pA_ + so0);                                   \
    fn.a[0][1] = *(const i32x4*)(pA_ + 2048 + so0);                            \
    SGB_DS2;                                                                   \
    MFMA_(0, 0, 0, fc); MFMA_(0, 0, 1, fc);                                    \
    SGB_MF2;                                                                   \
    fn.a[0][2] = *(const i32x4*)(pA_ + 4096 + so0);                            \
    fn.a[0][3] = *(const i32x4*)(pA_ + 6144 + so0);                            \
    SGB_DS2;                                                                   \
    MFMA_(0, 1, 0, fc); MFMA_(0, 1, 1, fc);                                    \
    SGB_MF2;                                                                   \
    fn.b[0][0] = *(const i32x4*)(pB_ + so0);                                   \
    fn.b[0][1] = *(const i32x4*)(pB_ + 2048 + so0);                            \
    SGB_DS2;                                                                   \
    MFMA_(0, 2, 0, fc); MFMA_(0, 2, 1, fc);                                    \
    SGB_MF2;                                                                   \
    fn.a[1][0] = *(const i32x4*)(pA_ + so1);                                   \
    fn.a[1][1] = *(const i32x4*)(pA_ + 2048 + so1);                            \
    SGB_DS2;                                                                   \
    MFMA_(0, 3, 0, fc); MFMA_(0, 3, 1, fc);                                    \
    SGB_MF2;                                                                   \
    fn.a[1][2] = *(const i32x4*)(pA_ + 4096 + so1);                            \
    fn.a[1][3] = *(const i32x4*)(pA_ + 6144 + so1);                            \
    SGB_DS2;                                                                   \
    MFMA_(1, 0, 0, fc); MFMA_(1, 0, 1, fc);                                    \
    SGB_MF2;                                                                   \
    fn.b[1][0] = *(const i32x4*)(pB_ + so1);                                   \
    fn.b[1][1] = *(const i32x4*)(pB_ + 2048 + so1);                            \
    SGB_DS2;                                                                   \
    MFMA_(1, 1, 0, fc); MFMA_(1, 1, 1, fc);                                    \
    SGB_MF2;                                                                   \
    MFMA_(1, 2, 0, fc); MFMA_(1, 2, 1, fc);                                    \
    MFMA_(1, 3, 0, fc); MFMA_(1, 3, 1, fc);                                    \
    SGB_MF4;                                                                   \
    __builtin_amdgcn_s_setprio(0);                                             \
  }

  // MFMA-only cluster (last tile)
#define MFMA16(f)                                                              \
  {                                                                            \
    __builtin_amdgcn_s_setprio(1);                                             \
    MFMA_(0, 0, 0, f); MFMA_(0, 0, 1, f); MFMA_(0, 1, 0, f); MFMA_(0, 1, 1, f);\
    MFMA_(0, 2, 0, f); MFMA_(0, 2, 1, f); MFMA_(0, 3, 0, f); MFMA_(0, 3, 1, f);\
    MFMA_(1, 0, 0, f); MFMA_(1, 0, 1, f); MFMA_(1, 1, 0, f); MFMA_(1, 1, 1, f);\
    MFMA_(1, 2, 0, f); MFMA_(1, 2, 1, f); MFMA_(1, 3, 0, f); MFMA_(1, 3, 1, f);\
    __builtin_amdgcn_s_setprio(0);                                             \
  }

  // iter t: wait t+1 landed -> barrier -> GLDS(t+3) -> interleaved
  // {read t+1 frags | MFMA tile t}.
#define ITER(t_, fc, fn, STAGE_STMT, VM_STMT)                                  \
  {                                                                            \
    VM_STMT;                                                                   \
    SB0;                                                                       \
    __builtin_amdgcn_s_barrier();                                              \
    SB0;                                                                       \
    STAGE_STMT;                                                                \
    SB0;                                                                       \
    CLUSTER(fc, fn, (t_) + 1);                                                 \
  }

  // ---- prologue: stage tiles 0,1,2 (12 loads); tile 0 readable.
  stage(0); stage(1); stage(2);
  VM8;  // 12 outstanding -> <=8 means tile 0's 4 retired
  SB0;
  __builtin_amdgcn_s_barrier();
  SB0;
  READF(f0, 0);
  f0.b[1][2] = f0.b[1][1];  // neutralize dummy (unused anyway)

  // ---- main loop: trips I=0..29 cover t=0..59 (stages 3..62)
  for (int I = 0; I < 30; ++I) {
    const int t0 = 2 * I;
    ITER(t0,     f0, f1, stage(t0 + 3), VM4);
    ITER(t0 + 1, f1, f0, stage(t0 + 4), VM4);
  }
  // ---- tail: t=60 (stage 63), 61, 62, then t=63 from registers
  ITER(60, f0, f1, stage(63), VM4);
  ITER(61, f1, f0, NOPX, VM4);
  ITER(62, f0, f1, NOPX, VM0);
  MFMA16(f1);  // t=63 (lgkm use-wait covers f1)
#undef ITER
#undef MFMA16
#undef CLUSTER
#undef READF
#undef MFMA_

  // ---- epilogue: 32x32 C/D layout col=lane&31, row=(r&3)+8*(r>>2)+4*(lane>>5)
  const int col0 = n0 + wn * 64 + (lane & 31);
  const float bv0 = bias[col0];
  const float bv1 = bias[col0 + 32];
#pragma unroll
  for (int m = 0; m < 4; m++) {
    const int rb = m0 + wm * 128 + m * 32 + ((lane >> 5) << 2);
#pragma unroll
    for (int r = 0; r < 16; r++) {
      const int row = rb + (r & 3) + ((r >> 2) << 3);
      const float sc = scales[row];
      float* cp = C + (size_t)row * N_OUT + col0;
      cp[0]  = (float)acc[m][0][r] * sc + bv0;
      cp[32] = (float)acc[m][1][r] * sc + bv1;
    }
  }
}

// emergency fallback if ws too small (correct but slow)
__global__ void fallback_gemm(const float* __restrict__ x, const float* __restrict__ w,
                              const float* __restrict__ bias, float* __restrict__ out) {
  int idx = blockIdx.x * blockDim.x + threadIdx.x;
  if (idx >= M_TOK * N_OUT) return;
  int row = idx / N_OUT, col = idx % N_OUT;
  const float* xp = x + (size_t)row * K_IN;
  const float* wp = w + (size_t)col * K_IN;
  float s = 0.f;
  for (int k = 0; k < K_IN; k++) {
    float wv = wp[k];
    float sg = wv > 0.f ? 1.f : (wv < 0.f ? -1.f : 0.f);
    s += xp[k] * sg;
  }
  out[idx] = s + bias[col];
}

extern "C" void kernel_launch(void* const* d_in, const int* in_sizes, int n_in,
                              void* d_out, int out_size, void* d_ws, size_t ws_size,
                              hipStream_t stream) {
  const float* x    = (const float*)d_in[0];
  const float* w    = (const float*)d_in[1];
  const float* bias = (const float*)d_in[2];
  float* out = (float*)d_out;

  const size_t xq_bytes = (size_t)M_TOK * K_IN;           // 32 MiB
  const size_t wq_bytes = (size_t)N_OUT * K_IN;           // 16 MiB
  const size_t sc_bytes = (size_t)M_TOK * sizeof(float);  // 32 KiB

  if (ws_size < xq_bytes + wq_bytes + sc_bytes) {
    int total = M_TOK * N_OUT;
    fallback_gemm<<<(total + 255) / 256, 256, 0, stream>>>(x, w, bias, out);
    return;
  }

  char*  xq = (char*)d_ws;
  char*  wq = (char*)d_ws + xq_bytes;
  float* sc = (float*)((char*)d_ws + xq_bytes + wq_bytes);

  // one fused quant launch: 8192 x-row blocks + 4096 w-sign blocks
  quant_fused<<<M_TOK + (N_OUT * K_IN / 4) / 1024, 256, 0, stream>>>(x, w, xq, wq, sc);

  // 32 x 16 = 512 blocks of 512 threads (8 waves), 128 KB LDS -> 1 block/CU
  gemm_bin_i8<<<512, 512, 0, stream>>>(xq, wq, sc, bias, out);
}